// Round 10
// baseline (977.042 us; speedup 1.0000x reference)
//
#include <hip/hip_runtime.h>

#define HD 64

typedef __attribute__((ext_vector_type(8))) short bf16x8;
typedef __attribute__((ext_vector_type(4))) float f32x4;

#define MFMA16(a, b, c) __builtin_amdgcn_mfma_f32_16x16x32_bf16(a, b, c, 0, 0, 0)

__device__ __forceinline__ float relu(float x) { return x > 0.f ? x : 0.f; }

__device__ __forceinline__ unsigned short f2bf(float f) {
  unsigned u = __float_as_uint(f);
  u += 0x7fff + ((u >> 16) & 1);
  return (unsigned short)(u >> 16);
}
__device__ __forceinline__ float bf2f(short s) {
  return __uint_as_float(((unsigned)(unsigned short)s) << 16);
}
__device__ __forceinline__ bf16x8 ldbf8(const unsigned short* p) {
  return *reinterpret_cast<const bf16x8*>(p);
}
__device__ __forceinline__ float4 ldf4(const float* p) {
  return *reinterpret_cast<const float4*>(p);
}

// ---------- weight convert+transpose: [B][K][Nc] f32 -> [B][Nc][K] bf16 ----------
__global__ __launch_bounds__(256) void k_wt(const float* __restrict__ in,
                                            unsigned short* __restrict__ out,
                                            int K, int Nc) {
  int total = K * Nc;
  int idx = blockIdx.x * 256 + threadIdx.x;
  int b = blockIdx.y;
  if (idx >= total) return;
  int n = idx / K, k = idx - n * K;
  out[(size_t)b * total + idx] = f2bf(in[(size_t)b * total + (size_t)k * Nc + n]);
}

// ---------- CSR build ----------
__global__ __launch_bounds__(256) void k_hist(const int* __restrict__ ei,
                                              int* __restrict__ deg, long long E_) {
  long long eid = (long long)blockIdx.x * 256 + threadIdx.x;
  if (eid >= E_) return;
  atomicAdd(deg + ei[E_ + eid], 1);
}

__global__ __launch_bounds__(1024) void k_scan(const int* __restrict__ deg,
                                               int* __restrict__ cnt, int N_) {
  __shared__ int s[1024];
  int t = threadIdx.x;
  int chunk = (N_ + 1023) / 1024;
  int lo = t * chunk, hi = lo + chunk;
  if (lo > N_) lo = N_;
  if (hi > N_) hi = N_;
  int sum = 0;
  for (int i = lo; i < hi; ++i) sum += deg[i];
  s[t] = sum;
  __syncthreads();
  for (int o = 1; o < 1024; o <<= 1) {
    int v = (t >= o) ? s[t - o] : 0;
    __syncthreads();
    s[t] += v;
    __syncthreads();
  }
  int base = (t == 0) ? 0 : s[t - 1];
  for (int i = lo; i < hi; ++i) {
    cnt[i] = base;
    base += deg[i];
  }
}

// packs (perm, src, dst) into one int4 -> 1 write-allocate line per edge, 1 load per consumer
__global__ __launch_bounds__(256) void k_scatter(const int* __restrict__ ei,
                                                 int* __restrict__ cnt,
                                                 int4* __restrict__ idx4, long long E_) {
  long long eid = (long long)blockIdx.x * 256 + threadIdx.x;
  if (eid >= E_) return;
  int s = ei[eid], d = ei[E_ + eid];
  int pos = atomicAdd(cnt + d, 1);
  idx4[pos] = make_int4((int)eid, s, d, 0);
}
// after k_scatter: cnt[n] == end offset of node n's edge range; start = cnt[n-1]

// ---------- node encoder ----------
__global__ __launch_bounds__(256) void k_node_enc(
    const float* __restrict__ nf, const float* __restrict__ W,
    const float* __restrict__ b, unsigned short* __restrict__ h, int N_) {
  int t = blockIdx.x * 256 + threadIdx.x;
  int n = t >> 6, j = t & 63;
  if (n >= N_) return;
  float x0 = nf[(size_t)n * 2 + 0], x1 = nf[(size_t)n * 2 + 1];
  h[t] = f2bf(relu(fmaf(x0, W[j], fmaf(x1, W[HD + j], b[j]))));
}

// ---------- round-0 precompute: H12 = [h@W1 + b_edge | h@W2] bf16 [N][128] ----------
__global__ __launch_bounds__(256) void k_pre(
    const unsigned short* __restrict__ h, const unsigned short* __restrict__ W12t,
    const float* __restrict__ be0, unsigned short* __restrict__ H12, int ntiles) {
  __shared__ __align__(16) float s[4][16][68];
  int wid = threadIdx.x >> 6, l = threadIdx.x & 63;
  int tile = blockIdx.x * 4 + wid;
  int lr = l & 15, lk = l >> 4;
  if (tile >= ntiles) return;
  int r0 = tile * 16;
  const unsigned short* hp = h + (size_t)(r0 + lr) * HD;
  f32x4 a1[4] = {}, a2[4] = {};
#pragma unroll
  for (int kk = 0; kk < 2; ++kk) {
    bf16x8 a = ldbf8(hp + kk * 32 + lk * 8);
#pragma unroll
    for (int nt = 0; nt < 4; ++nt) {
      bf16x8 b1 = ldbf8(W12t + (size_t)(nt * 16 + lr) * 64 + kk * 32 + lk * 8);
      bf16x8 b2 = ldbf8(W12t + 4096 + (size_t)(nt * 16 + lr) * 64 + kk * 32 + lk * 8);
      a1[nt] = MFMA16(a, b1, a1[nt]);
      a2[nt] = MFMA16(a, b2, a2[nt]);
    }
  }
  int erow = l >> 2, c0 = (l & 3) * 16;
#pragma unroll
  for (int nt = 0; nt < 4; ++nt) {
    float bias = be0[nt * 16 + lr];
#pragma unroll
    for (int i = 0; i < 4; ++i) s[wid][lk * 4 + i][nt * 16 + lr] = a1[nt][i] + bias;
  }
  {
    bf16x8 o0, o1;
#pragma unroll
    for (int j = 0; j < 8; ++j) {
      o0[j] = f2bf(s[wid][erow][c0 + j]);
      o1[j] = f2bf(s[wid][erow][c0 + 8 + j]);
    }
    unsigned short* op = H12 + (size_t)(r0 + erow) * 128 + c0;
    *reinterpret_cast<bf16x8*>(op) = o0;
    *reinterpret_cast<bf16x8*>(op + 8) = o1;
  }
#pragma unroll
  for (int nt = 0; nt < 4; ++nt)
#pragma unroll
    for (int i = 0; i < 4; ++i) s[wid][lk * 4 + i][nt * 16 + lr] = a2[nt][i];
  {
    bf16x8 o0, o1;
#pragma unroll
    for (int j = 0; j < 8; ++j) {
      o0[j] = f2bf(s[wid][erow][c0 + j]);
      o1[j] = f2bf(s[wid][erow][c0 + 8 + j]);
    }
    unsigned short* op = H12 + (size_t)(r0 + erow) * 128 + 64 + c0;
    *reinterpret_cast<bf16x8*>(op) = o0;
    *reinterpret_cast<bf16x8*>(op + 8) = o1;
  }
}

// ---------- edge kernel: m = relu(H1[src] + H2[dst] + e@W3); 2 tiles/wave ILP ----------
// LAST round: skip m->e store; in-LDS segmented column-sum + fp32 atomicAdd into aggr
// (m traffic for round R-1 drops from 204 MB to ~13 MB).
template <bool FUSE_ENC, bool LAST>
__global__ __launch_bounds__(256) void k_edge2(
    unsigned short* __restrict__ e, const unsigned short* __restrict__ H12,
    const int4* __restrict__ idx4, const unsigned short* __restrict__ W3t,
    const float* __restrict__ ea, const float* __restrict__ We,
    const float* __restrict__ be, float* __restrict__ aggr,
    int netiles, int E_) {
  __shared__ __align__(16) float smf[4][16][68];
  int wid = threadIdx.x >> 6, l = threadIdx.x & 63;
  int tp = blockIdx.x * 4 + wid;  // tile pair
  int lr = l & 15, lk = l >> 4;
  int erow = l >> 2, c0 = (l & 3) * 16;
  int t0 = tp * 2;
  if (t0 >= netiles) return;

  int r0[2] = {t0 * 16, (t0 + 1) * 16};
  bool tv[2] = {true, (t0 + 1) < netiles};

  // ---- early gathers for both tiles (independent chains) ----
  bf16x8 g1a[2], g1b[2], g2a[2], g2b[2];
#pragma unroll
  for (int u = 0; u < 2; ++u) {
    int4 q = idx4[min(r0[u] + erow, E_ - 1)];
    const unsigned short* h1p = H12 + (size_t)q.y * 128 + c0;
    const unsigned short* h2p = H12 + (size_t)q.z * 128 + 64 + c0;
    g1a[u] = ldbf8(h1p);
    g1b[u] = ldbf8(h1p + 8);
    g2a[u] = ldbf8(h2p);
    g2b[u] = ldbf8(h2p + 8);
  }

  // ---- A fragments for both tiles ----
  bf16x8 afrag[2][2];
#pragma unroll
  for (int u = 0; u < 2; ++u) {
    int ia = min(r0[u] + lr, E_ - 1);
    if (FUSE_ENC) {
      int eid = idx4[ia].x;
      float4 row = ldf4(ea + (size_t)eid * 4);
#pragma unroll
      for (int kk = 0; kk < 2; ++kk) {
        int j0 = kk * 32 + lk * 8;
        float4 b0 = ldf4(be + j0), b1 = ldf4(be + j0 + 4);
        float v[8] = {b0.x, b0.y, b0.z, b0.w, b1.x, b1.y, b1.z, b1.w};
#pragma unroll
        for (int c = 0; c < 4; ++c) {
          float x = (c == 0) ? row.x : (c == 1) ? row.y : (c == 2) ? row.z : row.w;
          float4 w0 = ldf4(We + c * 64 + j0), w1 = ldf4(We + c * 64 + j0 + 4);
          v[0] = fmaf(x, w0.x, v[0]); v[1] = fmaf(x, w0.y, v[1]);
          v[2] = fmaf(x, w0.z, v[2]); v[3] = fmaf(x, w0.w, v[3]);
          v[4] = fmaf(x, w1.x, v[4]); v[5] = fmaf(x, w1.y, v[5]);
          v[6] = fmaf(x, w1.z, v[6]); v[7] = fmaf(x, w1.w, v[7]);
        }
#pragma unroll
        for (int q = 0; q < 8; ++q) afrag[u][kk][q] = (short)f2bf(relu(v[q]));
      }
    } else {
      const unsigned short* ep = e + (size_t)ia * HD;
      afrag[u][0] = ldbf8(ep + lk * 8);
      afrag[u][1] = ldbf8(ep + 32 + lk * 8);
    }
  }

  // ---- e @ W3 for both tiles (W3 fragments shared) ----
  f32x4 acc0[4] = {}, acc1[4] = {};
#pragma unroll
  for (int kk = 0; kk < 2; ++kk) {
#pragma unroll
    for (int nt = 0; nt < 4; ++nt) {
      bf16x8 bb = ldbf8(W3t + (size_t)(nt * 16 + lr) * 64 + kk * 32 + lk * 8);
      acc0[nt] = MFMA16(afrag[0][kk], bb, acc0[nt]);
      acc1[nt] = MFMA16(afrag[1][kk], bb, acc1[nt]);
    }
  }

  // ---- sequential combine per tile through ONE shared buffer (wave-private) ----
  float segsum = 0.f;
  int prev = LAST ? idx4[r0[0]].z : 0;
#pragma unroll
  for (int u = 0; u < 2; ++u) {
    if (!tv[u]) continue;
#pragma unroll
    for (int nt = 0; nt < 4; ++nt)
#pragma unroll
      for (int i = 0; i < 4; ++i)
        smf[wid][lk * 4 + i][nt * 16 + lr] = (u == 0) ? acc0[nt][i] : acc1[nt][i];
    float g1f[16], g2f[16];
#pragma unroll
    for (int j = 0; j < 8; ++j) {
      g1f[j] = bf2f(g1a[u][j]); g1f[8 + j] = bf2f(g1b[u][j]);
      g2f[j] = bf2f(g2a[u][j]); g2f[8 + j] = bf2f(g2b[u][j]);
    }
    float v[16];
#pragma unroll
    for (int q = 0; q < 4; ++q) {
      float4 s4 = ldf4(&smf[wid][erow][c0 + q * 4]);
      v[q * 4 + 0] = relu(s4.x + g1f[q * 4 + 0] + g2f[q * 4 + 0]);
      v[q * 4 + 1] = relu(s4.y + g1f[q * 4 + 1] + g2f[q * 4 + 1]);
      v[q * 4 + 2] = relu(s4.z + g1f[q * 4 + 2] + g2f[q * 4 + 2]);
      v[q * 4 + 3] = relu(s4.w + g1f[q * 4 + 3] + g2f[q * 4 + 3]);
    }
    if (!LAST) {
      bf16x8 o0, o1;
#pragma unroll
      for (int j = 0; j < 8; ++j) {
        o0[j] = f2bf(v[j]);
        o1[j] = f2bf(v[8 + j]);
      }
      size_t eb = ((size_t)r0[u] + erow) * HD + c0;
      *reinterpret_cast<bf16x8*>(&e[eb]) = o0;
      *reinterpret_cast<bf16x8*>(&e[eb + 8]) = o1;
    } else {
      // write final m rows back to own slice (wave-private LDS, in-order)
#pragma unroll
      for (int q = 0; q < 4; ++q)
        *reinterpret_cast<float4*>(&smf[wid][erow][c0 + q * 4]) =
            make_float4(v[q * 4], v[q * 4 + 1], v[q * 4 + 2], v[q * 4 + 3]);
      // segmented column-sum (lane l owns col l; dst-sorted, carried across tiles)
#pragma unroll
      for (int r = 0; r < 16; ++r) {
        int i = r0[u] + r;
        if (i >= E_) break;
        int dc = idx4[i].z;
        if (dc != prev) {
          atomicAdd(aggr + (size_t)prev * HD + l, segsum);
          segsum = 0.f;
          prev = dc;
        }
        segsum += smf[wid][r][l];
      }
    }
  }
  if (LAST) atomicAdd(aggr + (size_t)prev * HD + l, segsum);
}

// ---------- node kernel: aggregation (CSR m-read, or fp32 aggr on last round)
//            + node MLP + fused next-round H12 ----------
__global__ __launch_bounds__(256) void k_node_csr(
    unsigned short* __restrict__ h, const unsigned short* __restrict__ m,
    const int* __restrict__ cnt,  // end offsets
    const unsigned short* __restrict__ Wt, const float* __restrict__ b,
    const unsigned short* __restrict__ W12t,  // next round [W1|W2], or null
    const float* __restrict__ be_next,        // next round edge bias
    unsigned short* __restrict__ H12,
    const float* __restrict__ aggr_in,        // non-null on last round
    int ntiles) {
  __shared__ __align__(16) float smf[4][16][68];
  int wid = threadIdx.x >> 6, l = threadIdx.x & 63;
  int tile = blockIdx.x * 4 + wid;
  if (tile >= ntiles) return;
  int r0 = tile * 16;
  int lr = l & 15, lk = l >> 4;

  bf16x8 aagg[2];
  if (aggr_in) {
    // last round: direct fp32 aggr read (pre-summed by edge kernel)
#pragma unroll
    for (int kk = 0; kk < 2; ++kk) {
      const float* ap = aggr_in + (size_t)(r0 + lr) * HD + kk * 32 + lk * 8;
      float4 f0 = ldf4(ap), f1 = ldf4(ap + 4);
      aagg[kk][0] = f2bf(f0.x); aagg[kk][1] = f2bf(f0.y);
      aagg[kk][2] = f2bf(f0.z); aagg[kk][3] = f2bf(f0.w);
      aagg[kk][4] = f2bf(f1.x); aagg[kk][5] = f2bf(f1.y);
      aagg[kk][6] = f2bf(f1.z); aagg[kk][7] = f2bf(f1.w);
    }
  } else {
    // ---- CSR aggregation: 4 lanes per node, 16 cols per lane ----
    int node = r0 + lr;
    int q16 = lk * 16;
    int beg = (node == 0) ? 0 : cnt[node - 1];
    int end = cnt[node];
    float s0[16];
#pragma unroll
    for (int j = 0; j < 16; ++j) s0[j] = 0.f;
    for (int i = beg; i < end; ++i) {
      const unsigned short* mp = m + (size_t)i * HD + q16;
      bf16x8 v0 = ldbf8(mp);
      bf16x8 v1 = ldbf8(mp + 8);
#pragma unroll
      for (int j = 0; j < 8; ++j) {
        s0[j] += bf2f(v0[j]);
        s0[8 + j] += bf2f(v1[j]);
      }
    }
#pragma unroll
    for (int j = 0; j < 16; ++j) smf[wid][lr][q16 + j] = s0[j];
#pragma unroll
    for (int kk = 0; kk < 2; ++kk) {
      const float* sp = &smf[wid][lr][kk * 32 + lk * 8];
      float4 f0 = ldf4(sp), f1 = ldf4(sp + 4);
      aagg[kk][0] = f2bf(f0.x); aagg[kk][1] = f2bf(f0.y);
      aagg[kk][2] = f2bf(f0.z); aagg[kk][3] = f2bf(f0.w);
      aagg[kk][4] = f2bf(f1.x); aagg[kk][5] = f2bf(f1.y);
      aagg[kk][6] = f2bf(f1.z); aagg[kk][7] = f2bf(f1.w);
    }
  }

  f32x4 acc[4] = {};
#pragma unroll
  for (int kk = 0; kk < 4; ++kk) {
    bf16x8 a = (kk < 2) ? ldbf8(h + (size_t)(r0 + lr) * HD + kk * 32 + lk * 8)
                        : aagg[kk - 2];
#pragma unroll
    for (int nt = 0; nt < 4; ++nt) {
      bf16x8 bb = ldbf8(Wt + (size_t)(kk >> 1) * 4096 +
                        (size_t)(nt * 16 + lr) * 64 + (kk & 1) * 32 + lk * 8);
      acc[nt] = MFMA16(a, bb, acc[nt]);
    }
  }

  // ---- relu + transpose -> new h ----
#pragma unroll
  for (int nt = 0; nt < 4; ++nt) {
    float bias = b[nt * 16 + lr];
#pragma unroll
    for (int i = 0; i < 4; ++i)
      smf[wid][lk * 4 + i][nt * 16 + lr] = relu(acc[nt][i] + bias);
  }
  int erow = l >> 2, c0 = (l & 3) * 16;
  {
    bf16x8 o0, o1;
#pragma unroll
    for (int j = 0; j < 8; ++j) {
      o0[j] = f2bf(smf[wid][erow][c0 + j]);
      o1[j] = f2bf(smf[wid][erow][c0 + 8 + j]);
    }
    size_t hb = (size_t)(r0 + erow) * HD + c0;
    *reinterpret_cast<bf16x8*>(&h[hb]) = o0;
    *reinterpret_cast<bf16x8*>(&h[hb + 8]) = o1;
  }

  if (!W12t) return;

  // ---- fused next-round H12 = [h@W1 + be_next | h@W2] bf16 ----
  bf16x8 ah[2];
#pragma unroll
  for (int kk = 0; kk < 2; ++kk) {
    const float* sp = &smf[wid][lr][kk * 32 + lk * 8];
    float4 f0 = ldf4(sp), f1 = ldf4(sp + 4);
    ah[kk][0] = f2bf(f0.x); ah[kk][1] = f2bf(f0.y);
    ah[kk][2] = f2bf(f0.z); ah[kk][3] = f2bf(f0.w);
    ah[kk][4] = f2bf(f1.x); ah[kk][5] = f2bf(f1.y);
    ah[kk][6] = f2bf(f1.z); ah[kk][7] = f2bf(f1.w);
  }
  f32x4 a1[4] = {}, a2[4] = {};
#pragma unroll
  for (int kk = 0; kk < 2; ++kk) {
#pragma unroll
    for (int nt = 0; nt < 4; ++nt) {
      bf16x8 b1 = ldbf8(W12t + (size_t)(nt * 16 + lr) * 64 + kk * 32 + lk * 8);
      bf16x8 b2 = ldbf8(W12t + 4096 + (size_t)(nt * 16 + lr) * 64 + kk * 32 + lk * 8);
      a1[nt] = MFMA16(ah[kk], b1, a1[nt]);
      a2[nt] = MFMA16(ah[kk], b2, a2[nt]);
    }
  }
#pragma unroll
  for (int nt = 0; nt < 4; ++nt) {
    float bias = be_next[nt * 16 + lr];
#pragma unroll
    for (int i = 0; i < 4; ++i)
      smf[wid][lk * 4 + i][nt * 16 + lr] = a1[nt][i] + bias;
  }
  {
    bf16x8 o0, o1;
#pragma unroll
    for (int j = 0; j < 8; ++j) {
      o0[j] = f2bf(smf[wid][erow][c0 + j]);
      o1[j] = f2bf(smf[wid][erow][c0 + 8 + j]);
    }
    unsigned short* op = H12 + (size_t)(r0 + erow) * 128 + c0;
    *reinterpret_cast<bf16x8*>(op) = o0;
    *reinterpret_cast<bf16x8*>(op + 8) = o1;
  }
#pragma unroll
  for (int nt = 0; nt < 4; ++nt)
#pragma unroll
    for (int i = 0; i < 4; ++i)
      smf[wid][lk * 4 + i][nt * 16 + lr] = a2[nt][i];
  {
    bf16x8 o0, o1;
#pragma unroll
    for (int j = 0; j < 8; ++j) {
      o0[j] = f2bf(smf[wid][erow][c0 + j]);
      o1[j] = f2bf(smf[wid][erow][c0 + 8 + j]);
    }
    unsigned short* op = H12 + (size_t)(r0 + erow) * 128 + 64 + c0;
    *reinterpret_cast<bf16x8*>(op) = o0;
    *reinterpret_cast<bf16x8*>(op + 8) = o1;
  }
}

// ---------- fused decoder + hm1: emb = h@Wdec + b (fp32 out), t = relu(emb@Whm1 + b) ----------
__global__ __launch_bounds__(256) void k_dec_hm1(
    const unsigned short* __restrict__ h,
    const unsigned short* __restrict__ Wdec, const float* __restrict__ bdec,
    const unsigned short* __restrict__ Whm1, const float* __restrict__ bhm1,
    float* __restrict__ emb, unsigned short* __restrict__ t_bf, int ntiles) {
  __shared__ __align__(16) float smf[4][16][68];
  int wid = threadIdx.x >> 6, l = threadIdx.x & 63;
  int tile = blockIdx.x * 4 + wid;
  if (tile >= ntiles) return;
  int r0 = tile * 16;
  int lr = l & 15, lk = l >> 4;
  int erow = l >> 2, c0 = (l & 3) * 16;

  f32x4 acc[4] = {};
#pragma unroll
  for (int kk = 0; kk < 2; ++kk) {
    bf16x8 a = ldbf8(h + (size_t)(r0 + lr) * HD + kk * 32 + lk * 8);
#pragma unroll
    for (int nt = 0; nt < 4; ++nt) {
      bf16x8 bb = ldbf8(Wdec + (size_t)(nt * 16 + lr) * HD + kk * 32 + lk * 8);
      acc[nt] = MFMA16(a, bb, acc[nt]);
    }
  }
#pragma unroll
  for (int nt = 0; nt < 4; ++nt) {
    float bias = bdec[nt * 16 + lr];
#pragma unroll
    for (int i = 0; i < 4; ++i)
      smf[wid][lk * 4 + i][nt * 16 + lr] = acc[nt][i] + bias;
  }
  // emb fp32 out (coalesced)
#pragma unroll
  for (int q = 0; q < 4; ++q)
    *reinterpret_cast<float4*>(emb + (size_t)(r0 + erow) * HD + c0 + q * 4) =
        ldf4(&smf[wid][erow][c0 + q * 4]);
  // hm1 A-fragments from LDS
  bf16x8 ah[2];
#pragma unroll
  for (int kk = 0; kk < 2; ++kk) {
    const float* sp = &smf[wid][lr][kk * 32 + lk * 8];
    float4 f0 = ldf4(sp), f1 = ldf4(sp + 4);
    ah[kk][0] = f2bf(f0.x); ah[kk][1] = f2bf(f0.y);
    ah[kk][2] = f2bf(f0.z); ah[kk][3] = f2bf(f0.w);
    ah[kk][4] = f2bf(f1.x); ah[kk][5] = f2bf(f1.y);
    ah[kk][6] = f2bf(f1.z); ah[kk][7] = f2bf(f1.w);
  }
  f32x4 acc2[4] = {};
#pragma unroll
  for (int kk = 0; kk < 2; ++kk) {
#pragma unroll
    for (int nt = 0; nt < 4; ++nt) {
      bf16x8 bb = ldbf8(Whm1 + (size_t)(nt * 16 + lr) * HD + kk * 32 + lk * 8);
      acc2[nt] = MFMA16(ah[kk], bb, acc2[nt]);
    }
  }
#pragma unroll
  for (int nt = 0; nt < 4; ++nt) {
    float bias = bhm1[nt * 16 + lr];
#pragma unroll
    for (int i = 0; i < 4; ++i)
      smf[wid][lk * 4 + i][nt * 16 + lr] = relu(acc2[nt][i] + bias);
  }
  {
    bf16x8 o0, o1;
#pragma unroll
    for (int j = 0; j < 8; ++j) {
      o0[j] = f2bf(smf[wid][erow][c0 + j]);
      o1[j] = f2bf(smf[wid][erow][c0 + 8 + j]);
    }
    size_t tb = (size_t)(r0 + erow) * HD + c0;
    *reinterpret_cast<bf16x8*>(&t_bf[tb]) = o0;
    *reinterpret_cast<bf16x8*>(&t_bf[tb + 8]) = o1;
  }
}

// ---------- heatmap head: [N,64] @ [64,1024] + b (nontemporal logits store) ----------
__global__ __launch_bounds__(256) void k_head_mfma(
    const unsigned short* __restrict__ A, const unsigned short* __restrict__ Wt,
    const float* __restrict__ b2, float* __restrict__ out) {
  __shared__ __align__(16) float sf[4][16][68];
  int wid = threadIdx.x >> 6, l = threadIdx.x & 63;
  int task = blockIdx.x * 4 + wid;
  int mt = task >> 4, ng = task & 15;
  int r0 = mt * 16, n0 = ng * 64;
  int lr = l & 15, lk = l >> 4;

  f32x4 acc[4] = {};
#pragma unroll
  for (int kk = 0; kk < 2; ++kk) {
    bf16x8 a = ldbf8(A + (size_t)(r0 + lr) * HD + kk * 32 + lk * 8);
#pragma unroll
    for (int nt = 0; nt < 4; ++nt) {
      bf16x8 bb = ldbf8(Wt + (size_t)(n0 + nt * 16 + lr) * HD + kk * 32 + lk * 8);
      acc[nt] = MFMA16(a, bb, acc[nt]);
    }
  }
#pragma unroll
  for (int nt = 0; nt < 4; ++nt) {
    int col = nt * 16 + lr;
    float bias = b2[n0 + col];
#pragma unroll
    for (int i = 0; i < 4; ++i) sf[wid][lk * 4 + i][col] = acc[nt][i] + bias;
  }
  int row = l >> 2, cb = (l & 3) * 16;
  float* op = out + (size_t)(r0 + row) * 1024 + n0 + cb;
#pragma unroll
  for (int q = 0; q < 4; ++q) {
    f32x4 vv = *reinterpret_cast<const f32x4*>(&sf[wid][row][cb + q * 4]);
    __builtin_nontemporal_store(vv, reinterpret_cast<f32x4*>(op + q * 4));
  }
}

extern "C" void kernel_launch(void* const* d_in, const int* in_sizes, int n_in,
                              void* d_out, int out_size, void* d_ws, size_t ws_size,
                              hipStream_t stream) {
  const float* node_features = (const float*)d_in[0];
  const float* edge_attr     = (const float*)d_in[1];
  const float* node_enc_W    = (const float*)d_in[2];
  const float* node_enc_b    = (const float*)d_in[3];
  const float* edge_enc_W    = (const float*)d_in[4];
  const float* edge_enc_b    = (const float*)d_in[5];
  const float* edge_mlp_W    = (const float*)d_in[6];
  const float* edge_mlp_b    = (const float*)d_in[7];
  const float* node_mlp_W    = (const float*)d_in[8];
  const float* node_mlp_b    = (const float*)d_in[9];
  const float* dec_W         = (const float*)d_in[10];
  const float* dec_b         = (const float*)d_in[11];
  const float* hm1_W         = (const float*)d_in[12];
  const float* hm1_b         = (const float*)d_in[13];
  const float* hm2_W         = (const float*)d_in[14];
  const float* hm2_b         = (const float*)d_in[15];
  const int*   edge_index    = (const int*)d_in[16];

  const int N_ = in_sizes[0] / 2;
  const long long E_ = in_sizes[1] / 4;
  const int R_ = in_sizes[7] / HD;

  // workspace carve-up (16B aligned chunks)
  char* p = (char*)d_ws;
  unsigned short* e_bf = (unsigned short*)p; p += (size_t)E_ * HD * 2;
  unsigned short* h_bf = (unsigned short*)p; p += (size_t)N_ * HD * 2;
  unsigned short* H12  = (unsigned short*)p; p += (size_t)N_ * 128 * 2;
  unsigned short* t_bf = (unsigned short*)p; p += (size_t)N_ * HD * 2;
  float* aggr = (float*)p;                   p += (size_t)N_ * HD * 4;
  unsigned short* wt_edge = (unsigned short*)p; p += (size_t)R_ * 3 * 64 * 64 * 2;
  unsigned short* wt_node = (unsigned short*)p; p += (size_t)R_ * 2 * 64 * 64 * 2;
  unsigned short* wt_dec = (unsigned short*)p;  p += 64 * 64 * 2;
  unsigned short* wt_hm1 = (unsigned short*)p;  p += 64 * 64 * 2;
  unsigned short* wt_hm2 = (unsigned short*)p;  p += 1024 * 64 * 2;
  int4* idx4 = (int4*)p; p += (size_t)E_ * 16;
  int* deg   = (int*)p; p += (size_t)N_ * 4;
  int* cnt   = (int*)p; p += (size_t)N_ * 4;

  // weight transposes: edge [R][3][64][64], node [R][2][64][64]
  k_wt<<<dim3((64 * 64 + 255) / 256, 3 * R_), 256, 0, stream>>>(edge_mlp_W, wt_edge, 64, 64);
  k_wt<<<dim3((64 * 64 + 255) / 256, 2 * R_), 256, 0, stream>>>(node_mlp_W, wt_node, 64, 64);
  k_wt<<<dim3((64 * 64 + 255) / 256, 1), 256, 0, stream>>>(dec_W, wt_dec, 64, 64);
  k_wt<<<dim3((64 * 64 + 255) / 256, 1), 256, 0, stream>>>(hm1_W, wt_hm1, 64, 64);
  k_wt<<<dim3((64 * 1024 + 255) / 256, 1), 256, 0, stream>>>(hm2_W, wt_hm2, 64, 1024);

  // dst-sorted edge order + CSR offsets
  const int e_blocks = (int)((E_ + 255) / 256);
  hipMemsetAsync(deg, 0, (size_t)N_ * 4, stream);
  k_hist<<<e_blocks, 256, 0, stream>>>(edge_index, deg, E_);
  k_scan<<<1, 1024, 0, stream>>>(deg, cnt, N_);
  k_scatter<<<e_blocks, 256, 0, stream>>>(edge_index, cnt, idx4, E_);

  const int nh_blocks = (int)(((size_t)N_ * HD + 255) / 256);
  k_node_enc<<<nh_blocks, 256, 0, stream>>>(node_features, node_enc_W, node_enc_b, h_bf, N_);

  const int netiles = (int)((E_ + 15) / 16);
  const int npairs = (netiles + 1) / 2;
  const int pe_blocks = (npairs + 3) / 4;
  const int ntiles = (N_ + 15) / 16;
  const int nblocks = (ntiles + 3) / 4;

  // H12 for round 0 (edge bias folded into H1)
  k_pre<<<nblocks, 256, 0, stream>>>(h_bf, wt_edge, edge_mlp_b, H12, ntiles);

  for (int r = 0; r < R_; ++r) {
    const unsigned short* W3t = wt_edge + (size_t)r * 3 * 4096 + 2 * 4096;
    bool fuse = (r == 0), last = (r == R_ - 1);
    if (last) hipMemsetAsync(aggr, 0, (size_t)N_ * HD * 4, stream);
    if (fuse && last)
      k_edge2<true, true><<<pe_blocks, 256, 0, stream>>>(
          e_bf, H12, idx4, W3t, edge_attr, edge_enc_W, edge_enc_b, aggr, netiles, (int)E_);
    else if (fuse)
      k_edge2<true, false><<<pe_blocks, 256, 0, stream>>>(
          e_bf, H12, idx4, W3t, edge_attr, edge_enc_W, edge_enc_b, nullptr, netiles, (int)E_);
    else if (last)
      k_edge2<false, true><<<pe_blocks, 256, 0, stream>>>(
          e_bf, H12, idx4, W3t, nullptr, nullptr, nullptr, aggr, netiles, (int)E_);
    else
      k_edge2<false, false><<<pe_blocks, 256, 0, stream>>>(
          e_bf, H12, idx4, W3t, nullptr, nullptr, nullptr, nullptr, netiles, (int)E_);

    const unsigned short* w12_next =
        (r + 1 < R_) ? (wt_edge + (size_t)(r + 1) * 3 * 4096) : nullptr;
    const float* be_next = edge_mlp_b + (size_t)(r + 1 < R_ ? r + 1 : 0) * HD;
    k_node_csr<<<nblocks, 256, 0, stream>>>(
        h_bf, e_bf, cnt, wt_node + (size_t)r * 2 * 4096,
        node_mlp_b + (size_t)r * HD, w12_next, be_next, H12,
        last ? aggr : nullptr, ntiles);
  }

  float* out_emb = (float*)d_out;
  float* out_log = out_emb + (size_t)N_ * HD;
  k_dec_hm1<<<nblocks, 256, 0, stream>>>(h_bf, wt_dec, dec_b, wt_hm1, hm1_b,
                                         out_emb, t_bf, ntiles);
  k_head_mfma<<<ntiles * 4, 256, 0, stream>>>(t_bf, wt_hm2, hm2_b, out_log);
}

// Round 11
// 806.975 us; speedup vs baseline: 1.2107x; 1.2107x over previous
//
#include <hip/hip_runtime.h>

#define HD 64

typedef __attribute__((ext_vector_type(8))) short bf16x8;
typedef __attribute__((ext_vector_type(4))) float f32x4;

#define MFMA16(a, b, c) __builtin_amdgcn_mfma_f32_16x16x32_bf16(a, b, c, 0, 0, 0)

__device__ __forceinline__ float relu(float x) { return x > 0.f ? x : 0.f; }

__device__ __forceinline__ unsigned short f2bf(float f) {
  unsigned u = __float_as_uint(f);
  u += 0x7fff + ((u >> 16) & 1);
  return (unsigned short)(u >> 16);
}
__device__ __forceinline__ float bf2f(short s) {
  return __uint_as_float(((unsigned)(unsigned short)s) << 16);
}
__device__ __forceinline__ bf16x8 ldbf8(const unsigned short* p) {
  return *reinterpret_cast<const bf16x8*>(p);
}
__device__ __forceinline__ float4 ldf4(const float* p) {
  return *reinterpret_cast<const float4*>(p);
}

// ---------- weight convert+transpose: [B][K][Nc] f32 -> [B][Nc][K] bf16 ----------
__global__ __launch_bounds__(256) void k_wt(const float* __restrict__ in,
                                            unsigned short* __restrict__ out,
                                            int K, int Nc) {
  int total = K * Nc;
  int idx = blockIdx.x * 256 + threadIdx.x;
  int b = blockIdx.y;
  if (idx >= total) return;
  int n = idx / K, k = idx - n * K;
  out[(size_t)b * total + idx] = f2bf(in[(size_t)b * total + (size_t)k * Nc + n]);
}

// ---------- CSR build ----------
__global__ __launch_bounds__(256) void k_hist(const int* __restrict__ ei,
                                              int* __restrict__ deg, long long E_) {
  long long eid = (long long)blockIdx.x * 256 + threadIdx.x;
  if (eid >= E_) return;
  atomicAdd(deg + ei[E_ + eid], 1);
}

__global__ __launch_bounds__(1024) void k_scan(const int* __restrict__ deg,
                                               int* __restrict__ cnt, int N_) {
  __shared__ int s[1024];
  int t = threadIdx.x;
  int chunk = (N_ + 1023) / 1024;
  int lo = t * chunk, hi = lo + chunk;
  if (lo > N_) lo = N_;
  if (hi > N_) hi = N_;
  int sum = 0;
  for (int i = lo; i < hi; ++i) sum += deg[i];
  s[t] = sum;
  __syncthreads();
  for (int o = 1; o < 1024; o <<= 1) {
    int v = (t >= o) ? s[t - o] : 0;
    __syncthreads();
    s[t] += v;
    __syncthreads();
  }
  int base = (t == 0) ? 0 : s[t - 1];
  for (int i = lo; i < hi; ++i) {
    cnt[i] = base;
    base += deg[i];
  }
}

// packs (perm, src, dst) into one int4 -> 1 write-allocate line per edge, 1 load per consumer
__global__ __launch_bounds__(256) void k_scatter(const int* __restrict__ ei,
                                                 int* __restrict__ cnt,
                                                 int4* __restrict__ idx4, long long E_) {
  long long eid = (long long)blockIdx.x * 256 + threadIdx.x;
  if (eid >= E_) return;
  int s = ei[eid], d = ei[E_ + eid];
  int pos = atomicAdd(cnt + d, 1);
  idx4[pos] = make_int4((int)eid, s, d, 0);
}
// after k_scatter: cnt[n] == end offset of node n's edge range; start = cnt[n-1]

// ---------- node encoder ----------
__global__ __launch_bounds__(256) void k_node_enc(
    const float* __restrict__ nf, const float* __restrict__ W,
    const float* __restrict__ b, unsigned short* __restrict__ h, int N_) {
  int t = blockIdx.x * 256 + threadIdx.x;
  int n = t >> 6, j = t & 63;
  if (n >= N_) return;
  float x0 = nf[(size_t)n * 2 + 0], x1 = nf[(size_t)n * 2 + 1];
  h[t] = f2bf(relu(fmaf(x0, W[j], fmaf(x1, W[HD + j], b[j]))));
}

// ---------- round-0 precompute: H12 = [h@W1 + b_edge | h@W2] bf16 [N][128] ----------
__global__ __launch_bounds__(256) void k_pre(
    const unsigned short* __restrict__ h, const unsigned short* __restrict__ W12t,
    const float* __restrict__ be0, unsigned short* __restrict__ H12, int ntiles) {
  __shared__ __align__(16) float s[4][16][68];
  int wid = threadIdx.x >> 6, l = threadIdx.x & 63;
  int tile = blockIdx.x * 4 + wid;
  int lr = l & 15, lk = l >> 4;
  if (tile >= ntiles) return;
  int r0 = tile * 16;
  const unsigned short* hp = h + (size_t)(r0 + lr) * HD;
  f32x4 a1[4] = {}, a2[4] = {};
#pragma unroll
  for (int kk = 0; kk < 2; ++kk) {
    bf16x8 a = ldbf8(hp + kk * 32 + lk * 8);
#pragma unroll
    for (int nt = 0; nt < 4; ++nt) {
      bf16x8 b1 = ldbf8(W12t + (size_t)(nt * 16 + lr) * 64 + kk * 32 + lk * 8);
      bf16x8 b2 = ldbf8(W12t + 4096 + (size_t)(nt * 16 + lr) * 64 + kk * 32 + lk * 8);
      a1[nt] = MFMA16(a, b1, a1[nt]);
      a2[nt] = MFMA16(a, b2, a2[nt]);
    }
  }
  int erow = l >> 2, c0 = (l & 3) * 16;
#pragma unroll
  for (int nt = 0; nt < 4; ++nt) {
    float bias = be0[nt * 16 + lr];
#pragma unroll
    for (int i = 0; i < 4; ++i) s[wid][lk * 4 + i][nt * 16 + lr] = a1[nt][i] + bias;
  }
  {
    bf16x8 o0, o1;
#pragma unroll
    for (int j = 0; j < 8; ++j) {
      o0[j] = f2bf(s[wid][erow][c0 + j]);
      o1[j] = f2bf(s[wid][erow][c0 + 8 + j]);
    }
    unsigned short* op = H12 + (size_t)(r0 + erow) * 128 + c0;
    *reinterpret_cast<bf16x8*>(op) = o0;
    *reinterpret_cast<bf16x8*>(op + 8) = o1;
  }
#pragma unroll
  for (int nt = 0; nt < 4; ++nt)
#pragma unroll
    for (int i = 0; i < 4; ++i) s[wid][lk * 4 + i][nt * 16 + lr] = a2[nt][i];
  {
    bf16x8 o0, o1;
#pragma unroll
    for (int j = 0; j < 8; ++j) {
      o0[j] = f2bf(s[wid][erow][c0 + j]);
      o1[j] = f2bf(s[wid][erow][c0 + 8 + j]);
    }
    unsigned short* op = H12 + (size_t)(r0 + erow) * 128 + 64 + c0;
    *reinterpret_cast<bf16x8*>(op) = o0;
    *reinterpret_cast<bf16x8*>(op + 8) = o1;
  }
}

// ---------- edge kernel: m = relu(H1[src] + H2[dst] + e@W3); 2 tiles/wave ILP ----------
// LAST round: skip m->e store; in-LDS segmented column-sum + fp32 atomicAdd into aggr.
template <bool FUSE_ENC, bool LAST>
__global__ __launch_bounds__(256) void k_edge2(
    unsigned short* __restrict__ e, const unsigned short* __restrict__ H12,
    const int4* __restrict__ idx4, const unsigned short* __restrict__ W3t,
    const float* __restrict__ ea, const float* __restrict__ We,
    const float* __restrict__ be, float* __restrict__ aggr,
    int netiles, int E_) {
  __shared__ __align__(16) float smf[4][16][68];
  int wid = threadIdx.x >> 6, l = threadIdx.x & 63;
  int tp = blockIdx.x * 4 + wid;  // tile pair
  int lr = l & 15, lk = l >> 4;
  int erow = l >> 2, c0 = (l & 3) * 16;
  int t0 = tp * 2;
  if (t0 >= netiles) return;

  int r0[2] = {t0 * 16, (t0 + 1) * 16};
  bool tv[2] = {true, (t0 + 1) < netiles};

  // ---- early gathers for both tiles (independent chains) ----
  bf16x8 g1a[2], g1b[2], g2a[2], g2b[2];
#pragma unroll
  for (int u = 0; u < 2; ++u) {
    int4 q = idx4[min(r0[u] + erow, E_ - 1)];
    const unsigned short* h1p = H12 + (size_t)q.y * 128 + c0;
    const unsigned short* h2p = H12 + (size_t)q.z * 128 + 64 + c0;
    g1a[u] = ldbf8(h1p);
    g1b[u] = ldbf8(h1p + 8);
    g2a[u] = ldbf8(h2p);
    g2b[u] = ldbf8(h2p + 8);
  }

  // ---- A fragments for both tiles ----
  bf16x8 afrag[2][2];
#pragma unroll
  for (int u = 0; u < 2; ++u) {
    int ia = min(r0[u] + lr, E_ - 1);
    if (FUSE_ENC) {
      int eid = idx4[ia].x;
      float4 row = ldf4(ea + (size_t)eid * 4);
#pragma unroll
      for (int kk = 0; kk < 2; ++kk) {
        int j0 = kk * 32 + lk * 8;
        float4 b0 = ldf4(be + j0), b1 = ldf4(be + j0 + 4);
        float v[8] = {b0.x, b0.y, b0.z, b0.w, b1.x, b1.y, b1.z, b1.w};
#pragma unroll
        for (int c = 0; c < 4; ++c) {
          float x = (c == 0) ? row.x : (c == 1) ? row.y : (c == 2) ? row.z : row.w;
          float4 w0 = ldf4(We + c * 64 + j0), w1 = ldf4(We + c * 64 + j0 + 4);
          v[0] = fmaf(x, w0.x, v[0]); v[1] = fmaf(x, w0.y, v[1]);
          v[2] = fmaf(x, w0.z, v[2]); v[3] = fmaf(x, w0.w, v[3]);
          v[4] = fmaf(x, w1.x, v[4]); v[5] = fmaf(x, w1.y, v[5]);
          v[6] = fmaf(x, w1.z, v[6]); v[7] = fmaf(x, w1.w, v[7]);
        }
#pragma unroll
        for (int q = 0; q < 8; ++q) afrag[u][kk][q] = (short)f2bf(relu(v[q]));
      }
    } else {
      const unsigned short* ep = e + (size_t)ia * HD;
      afrag[u][0] = ldbf8(ep + lk * 8);
      afrag[u][1] = ldbf8(ep + 32 + lk * 8);
    }
  }

  // ---- e @ W3 for both tiles (W3 fragments shared) ----
  f32x4 acc0[4] = {}, acc1[4] = {};
#pragma unroll
  for (int kk = 0; kk < 2; ++kk) {
#pragma unroll
    for (int nt = 0; nt < 4; ++nt) {
      bf16x8 bb = ldbf8(W3t + (size_t)(nt * 16 + lr) * 64 + kk * 32 + lk * 8);
      acc0[nt] = MFMA16(afrag[0][kk], bb, acc0[nt]);
      acc1[nt] = MFMA16(afrag[1][kk], bb, acc1[nt]);
    }
  }

  // ---- sequential combine per tile through ONE shared buffer (wave-private) ----
  float segsum = 0.f;
  int prev = LAST ? idx4[r0[0]].z : 0;
#pragma unroll
  for (int u = 0; u < 2; ++u) {
    if (!tv[u]) continue;
#pragma unroll
    for (int nt = 0; nt < 4; ++nt)
#pragma unroll
      for (int i = 0; i < 4; ++i)
        smf[wid][lk * 4 + i][nt * 16 + lr] = (u == 0) ? acc0[nt][i] : acc1[nt][i];
    float g1f[16], g2f[16];
#pragma unroll
    for (int j = 0; j < 8; ++j) {
      g1f[j] = bf2f(g1a[u][j]); g1f[8 + j] = bf2f(g1b[u][j]);
      g2f[j] = bf2f(g2a[u][j]); g2f[8 + j] = bf2f(g2b[u][j]);
    }
    float v[16];
#pragma unroll
    for (int q = 0; q < 4; ++q) {
      float4 s4 = ldf4(&smf[wid][erow][c0 + q * 4]);
      v[q * 4 + 0] = relu(s4.x + g1f[q * 4 + 0] + g2f[q * 4 + 0]);
      v[q * 4 + 1] = relu(s4.y + g1f[q * 4 + 1] + g2f[q * 4 + 1]);
      v[q * 4 + 2] = relu(s4.z + g1f[q * 4 + 2] + g2f[q * 4 + 2]);
      v[q * 4 + 3] = relu(s4.w + g1f[q * 4 + 3] + g2f[q * 4 + 3]);
    }
    if (!LAST) {
      bf16x8 o0, o1;
#pragma unroll
      for (int j = 0; j < 8; ++j) {
        o0[j] = f2bf(v[j]);
        o1[j] = f2bf(v[8 + j]);
      }
      size_t eb = ((size_t)r0[u] + erow) * HD + c0;
      *reinterpret_cast<bf16x8*>(&e[eb]) = o0;
      *reinterpret_cast<bf16x8*>(&e[eb + 8]) = o1;
    } else {
      // write final m rows back to own slice (wave-private LDS, in-order)
#pragma unroll
      for (int q = 0; q < 4; ++q)
        *reinterpret_cast<float4*>(&smf[wid][erow][c0 + q * 4]) =
            make_float4(v[q * 4], v[q * 4 + 1], v[q * 4 + 2], v[q * 4 + 3]);
      // segmented column-sum (lane l owns col l; dst-sorted, carried across tiles)
#pragma unroll
      for (int r = 0; r < 16; ++r) {
        int i = r0[u] + r;
        if (i >= E_) break;
        int dc = idx4[i].z;
        if (dc != prev) {
          atomicAdd(aggr + (size_t)prev * HD + l, segsum);
          segsum = 0.f;
          prev = dc;
        }
        segsum += smf[wid][r][l];
      }
    }
  }
  if (LAST) atomicAdd(aggr + (size_t)prev * HD + l, segsum);
}

// ---------- node kernel: aggregation (CSR m-read, or fp32 aggr on last round)
//            + node MLP + fused next-round H12 ----------
__global__ __launch_bounds__(256) void k_node_csr(
    unsigned short* __restrict__ h, const unsigned short* __restrict__ m,
    const int* __restrict__ cnt,  // end offsets
    const unsigned short* __restrict__ Wt, const float* __restrict__ b,
    const unsigned short* __restrict__ W12t,  // next round [W1|W2], or null
    const float* __restrict__ be_next,        // next round edge bias
    unsigned short* __restrict__ H12,
    const float* __restrict__ aggr_in,        // non-null on last round
    int ntiles) {
  __shared__ __align__(16) float smf[4][16][68];
  int wid = threadIdx.x >> 6, l = threadIdx.x & 63;
  int tile = blockIdx.x * 4 + wid;
  if (tile >= ntiles) return;
  int r0 = tile * 16;
  int lr = l & 15, lk = l >> 4;

  bf16x8 aagg[2];
  if (aggr_in) {
    // last round: direct fp32 aggr read (pre-summed by edge kernel)
#pragma unroll
    for (int kk = 0; kk < 2; ++kk) {
      const float* ap = aggr_in + (size_t)(r0 + lr) * HD + kk * 32 + lk * 8;
      float4 f0 = ldf4(ap), f1 = ldf4(ap + 4);
      aagg[kk][0] = f2bf(f0.x); aagg[kk][1] = f2bf(f0.y);
      aagg[kk][2] = f2bf(f0.z); aagg[kk][3] = f2bf(f0.w);
      aagg[kk][4] = f2bf(f1.x); aagg[kk][5] = f2bf(f1.y);
      aagg[kk][6] = f2bf(f1.z); aagg[kk][7] = f2bf(f1.w);
    }
  } else {
    // ---- CSR aggregation: 4 lanes per node, 16 cols per lane ----
    int node = r0 + lr;
    int q16 = lk * 16;
    int beg = (node == 0) ? 0 : cnt[node - 1];
    int end = cnt[node];
    float s0[16];
#pragma unroll
    for (int j = 0; j < 16; ++j) s0[j] = 0.f;
    for (int i = beg; i < end; ++i) {
      const unsigned short* mp = m + (size_t)i * HD + q16;
      bf16x8 v0 = ldbf8(mp);
      bf16x8 v1 = ldbf8(mp + 8);
#pragma unroll
      for (int j = 0; j < 8; ++j) {
        s0[j] += bf2f(v0[j]);
        s0[8 + j] += bf2f(v1[j]);
      }
    }
#pragma unroll
    for (int j = 0; j < 16; ++j) smf[wid][lr][q16 + j] = s0[j];
#pragma unroll
    for (int kk = 0; kk < 2; ++kk) {
      const float* sp = &smf[wid][lr][kk * 32 + lk * 8];
      float4 f0 = ldf4(sp), f1 = ldf4(sp + 4);
      aagg[kk][0] = f2bf(f0.x); aagg[kk][1] = f2bf(f0.y);
      aagg[kk][2] = f2bf(f0.z); aagg[kk][3] = f2bf(f0.w);
      aagg[kk][4] = f2bf(f1.x); aagg[kk][5] = f2bf(f1.y);
      aagg[kk][6] = f2bf(f1.z); aagg[kk][7] = f2bf(f1.w);
    }
  }

  f32x4 acc[4] = {};
#pragma unroll
  for (int kk = 0; kk < 4; ++kk) {
    bf16x8 a = (kk < 2) ? ldbf8(h + (size_t)(r0 + lr) * HD + kk * 32 + lk * 8)
                        : aagg[kk - 2];
#pragma unroll
    for (int nt = 0; nt < 4; ++nt) {
      bf16x8 bb = ldbf8(Wt + (size_t)(kk >> 1) * 4096 +
                        (size_t)(nt * 16 + lr) * 64 + (kk & 1) * 32 + lk * 8);
      acc[nt] = MFMA16(a, bb, acc[nt]);
    }
  }

  // ---- relu + transpose -> new h ----
#pragma unroll
  for (int nt = 0; nt < 4; ++nt) {
    float bias = b[nt * 16 + lr];
#pragma unroll
    for (int i = 0; i < 4; ++i)
      smf[wid][lk * 4 + i][nt * 16 + lr] = relu(acc[nt][i] + bias);
  }
  int erow = l >> 2, c0 = (l & 3) * 16;
  {
    bf16x8 o0, o1;
#pragma unroll
    for (int j = 0; j < 8; ++j) {
      o0[j] = f2bf(smf[wid][erow][c0 + j]);
      o1[j] = f2bf(smf[wid][erow][c0 + 8 + j]);
    }
    size_t hb = (size_t)(r0 + erow) * HD + c0;
    *reinterpret_cast<bf16x8*>(&h[hb]) = o0;
    *reinterpret_cast<bf16x8*>(&h[hb + 8]) = o1;
  }

  if (!W12t) return;

  // ---- fused next-round H12 = [h@W1 + be_next | h@W2] bf16 ----
  bf16x8 ah[2];
#pragma unroll
  for (int kk = 0; kk < 2; ++kk) {
    const float* sp = &smf[wid][lr][kk * 32 + lk * 8];
    float4 f0 = ldf4(sp), f1 = ldf4(sp + 4);
    ah[kk][0] = f2bf(f0.x); ah[kk][1] = f2bf(f0.y);
    ah[kk][2] = f2bf(f0.z); ah[kk][3] = f2bf(f0.w);
    ah[kk][4] = f2bf(f1.x); ah[kk][5] = f2bf(f1.y);
    ah[kk][6] = f2bf(f1.z); ah[kk][7] = f2bf(f1.w);
  }
  f32x4 a1[4] = {}, a2[4] = {};
#pragma unroll
  for (int kk = 0; kk < 2; ++kk) {
#pragma unroll
    for (int nt = 0; nt < 4; ++nt) {
      bf16x8 b1 = ldbf8(W12t + (size_t)(nt * 16 + lr) * 64 + kk * 32 + lk * 8);
      bf16x8 b2 = ldbf8(W12t + 4096 + (size_t)(nt * 16 + lr) * 64 + kk * 32 + lk * 8);
      a1[nt] = MFMA16(ah[kk], b1, a1[nt]);
      a2[nt] = MFMA16(ah[kk], b2, a2[nt]);
    }
  }
#pragma unroll
  for (int nt = 0; nt < 4; ++nt) {
    float bias = be_next[nt * 16 + lr];
#pragma unroll
    for (int i = 0; i < 4; ++i)
      smf[wid][lk * 4 + i][nt * 16 + lr] = a1[nt][i] + bias;
  }
  {
    bf16x8 o0, o1;
#pragma unroll
    for (int j = 0; j < 8; ++j) {
      o0[j] = f2bf(smf[wid][erow][c0 + j]);
      o1[j] = f2bf(smf[wid][erow][c0 + 8 + j]);
    }
    unsigned short* op = H12 + (size_t)(r0 + erow) * 128 + c0;
    *reinterpret_cast<bf16x8*>(op) = o0;
    *reinterpret_cast<bf16x8*>(op + 8) = o1;
  }
#pragma unroll
  for (int nt = 0; nt < 4; ++nt)
#pragma unroll
    for (int i = 0; i < 4; ++i)
      smf[wid][lk * 4 + i][nt * 16 + lr] = a2[nt][i];
  {
    bf16x8 o0, o1;
#pragma unroll
    for (int j = 0; j < 8; ++j) {
      o0[j] = f2bf(smf[wid][erow][c0 + j]);
      o1[j] = f2bf(smf[wid][erow][c0 + 8 + j]);
    }
    unsigned short* op = H12 + (size_t)(r0 + erow) * 128 + 64 + c0;
    *reinterpret_cast<bf16x8*>(op) = o0;
    *reinterpret_cast<bf16x8*>(op + 8) = o1;
  }
}

// ---------- fused decoder + hm1: emb = h@Wdec + b (fp32 out), t = relu(emb@Whm1 + b) ----------
__global__ __launch_bounds__(256) void k_dec_hm1(
    const unsigned short* __restrict__ h,
    const unsigned short* __restrict__ Wdec, const float* __restrict__ bdec,
    const unsigned short* __restrict__ Whm1, const float* __restrict__ bhm1,
    float* __restrict__ emb, unsigned short* __restrict__ t_bf, int ntiles) {
  __shared__ __align__(16) float smf[4][16][68];
  int wid = threadIdx.x >> 6, l = threadIdx.x & 63;
  int tile = blockIdx.x * 4 + wid;
  if (tile >= ntiles) return;
  int r0 = tile * 16;
  int lr = l & 15, lk = l >> 4;
  int erow = l >> 2, c0 = (l & 3) * 16;

  f32x4 acc[4] = {};
#pragma unroll
  for (int kk = 0; kk < 2; ++kk) {
    bf16x8 a = ldbf8(h + (size_t)(r0 + lr) * HD + kk * 32 + lk * 8);
#pragma unroll
    for (int nt = 0; nt < 4; ++nt) {
      bf16x8 bb = ldbf8(Wdec + (size_t)(nt * 16 + lr) * HD + kk * 32 + lk * 8);
      acc[nt] = MFMA16(a, bb, acc[nt]);
    }
  }
#pragma unroll
  for (int nt = 0; nt < 4; ++nt) {
    float bias = bdec[nt * 16 + lr];
#pragma unroll
    for (int i = 0; i < 4; ++i)
      smf[wid][lk * 4 + i][nt * 16 + lr] = acc[nt][i] + bias;
  }
  // emb fp32 out (coalesced)
#pragma unroll
  for (int q = 0; q < 4; ++q)
    *reinterpret_cast<float4*>(emb + (size_t)(r0 + erow) * HD + c0 + q * 4) =
        ldf4(&smf[wid][erow][c0 + q * 4]);
  // hm1 A-fragments from LDS
  bf16x8 ah[2];
#pragma unroll
  for (int kk = 0; kk < 2; ++kk) {
    const float* sp = &smf[wid][lr][kk * 32 + lk * 8];
    float4 f0 = ldf4(sp), f1 = ldf4(sp + 4);
    ah[kk][0] = f2bf(f0.x); ah[kk][1] = f2bf(f0.y);
    ah[kk][2] = f2bf(f0.z); ah[kk][3] = f2bf(f0.w);
    ah[kk][4] = f2bf(f1.x); ah[kk][5] = f2bf(f1.y);
    ah[kk][6] = f2bf(f1.z); ah[kk][7] = f2bf(f1.w);
  }
  f32x4 acc2[4] = {};
#pragma unroll
  for (int kk = 0; kk < 2; ++kk) {
#pragma unroll
    for (int nt = 0; nt < 4; ++nt) {
      bf16x8 bb = ldbf8(Whm1 + (size_t)(nt * 16 + lr) * HD + kk * 32 + lk * 8);
      acc2[nt] = MFMA16(ah[kk], bb, acc2[nt]);
    }
  }
#pragma unroll
  for (int nt = 0; nt < 4; ++nt) {
    float bias = bhm1[nt * 16 + lr];
#pragma unroll
    for (int i = 0; i < 4; ++i)
      smf[wid][lk * 4 + i][nt * 16 + lr] = relu(acc2[nt][i] + bias);
  }
  {
    bf16x8 o0, o1;
#pragma unroll
    for (int j = 0; j < 8; ++j) {
      o0[j] = f2bf(smf[wid][erow][c0 + j]);
      o1[j] = f2bf(smf[wid][erow][c0 + 8 + j]);
    }
    size_t tb = (size_t)(r0 + erow) * HD + c0;
    *reinterpret_cast<bf16x8*>(&t_bf[tb]) = o0;
    *reinterpret_cast<bf16x8*>(&t_bf[tb + 8]) = o1;
  }
}

// ---------- heatmap head: [N,64] @ [64,1024] + b (plain coalesced stores) ----------
__global__ __launch_bounds__(256) void k_head_mfma(
    const unsigned short* __restrict__ A, const unsigned short* __restrict__ Wt,
    const float* __restrict__ b2, float* __restrict__ out) {
  __shared__ __align__(16) float sf[4][16][68];
  int wid = threadIdx.x >> 6, l = threadIdx.x & 63;
  int task = blockIdx.x * 4 + wid;
  int mt = task >> 4, ng = task & 15;
  int r0 = mt * 16, n0 = ng * 64;
  int lr = l & 15, lk = l >> 4;

  f32x4 acc[4] = {};
#pragma unroll
  for (int kk = 0; kk < 2; ++kk) {
    bf16x8 a = ldbf8(A + (size_t)(r0 + lr) * HD + kk * 32 + lk * 8);
#pragma unroll
    for (int nt = 0; nt < 4; ++nt) {
      bf16x8 bb = ldbf8(Wt + (size_t)(n0 + nt * 16 + lr) * HD + kk * 32 + lk * 8);
      acc[nt] = MFMA16(a, bb, acc[nt]);
    }
  }
#pragma unroll
  for (int nt = 0; nt < 4; ++nt) {
    int col = nt * 16 + lr;
    float bias = b2[n0 + col];
#pragma unroll
    for (int i = 0; i < 4; ++i) sf[wid][lk * 4 + i][col] = acc[nt][i] + bias;
  }
  int row = l >> 2, cb = (l & 3) * 16;
  float* op = out + (size_t)(r0 + row) * 1024 + n0 + cb;
#pragma unroll
  for (int q = 0; q < 4; ++q)
    *reinterpret_cast<float4*>(op + q * 4) = ldf4(&sf[wid][row][cb + q * 4]);
}

extern "C" void kernel_launch(void* const* d_in, const int* in_sizes, int n_in,
                              void* d_out, int out_size, void* d_ws, size_t ws_size,
                              hipStream_t stream) {
  const float* node_features = (const float*)d_in[0];
  const float* edge_attr     = (const float*)d_in[1];
  const float* node_enc_W    = (const float*)d_in[2];
  const float* node_enc_b    = (const float*)d_in[3];
  const float* edge_enc_W    = (const float*)d_in[4];
  const float* edge_enc_b    = (const float*)d_in[5];
  const float* edge_mlp_W    = (const float*)d_in[6];
  const float* edge_mlp_b    = (const float*)d_in[7];
  const float* node_mlp_W    = (const float*)d_in[8];
  const float* node_mlp_b    = (const float*)d_in[9];
  const float* dec_W         = (const float*)d_in[10];
  const float* dec_b         = (const float*)d_in[11];
  const float* hm1_W         = (const float*)d_in[12];
  const float* hm1_b         = (const float*)d_in[13];
  const float* hm2_W         = (const float*)d_in[14];
  const float* hm2_b         = (const float*)d_in[15];
  const int*   edge_index    = (const int*)d_in[16];

  const int N_ = in_sizes[0] / 2;
  const long long E_ = in_sizes[1] / 4;
  const int R_ = in_sizes[7] / HD;

  // workspace carve-up (16B aligned chunks)
  char* p = (char*)d_ws;
  unsigned short* e_bf = (unsigned short*)p; p += (size_t)E_ * HD * 2;
  unsigned short* h_bf = (unsigned short*)p; p += (size_t)N_ * HD * 2;
  unsigned short* H12  = (unsigned short*)p; p += (size_t)N_ * 128 * 2;
  unsigned short* t_bf = (unsigned short*)p; p += (size_t)N_ * HD * 2;
  float* aggr = (float*)p;                   p += (size_t)N_ * HD * 4;
  unsigned short* wt_edge = (unsigned short*)p; p += (size_t)R_ * 3 * 64 * 64 * 2;
  unsigned short* wt_node = (unsigned short*)p; p += (size_t)R_ * 2 * 64 * 64 * 2;
  unsigned short* wt_dec = (unsigned short*)p;  p += 64 * 64 * 2;
  unsigned short* wt_hm1 = (unsigned short*)p;  p += 64 * 64 * 2;
  unsigned short* wt_hm2 = (unsigned short*)p;  p += 1024 * 64 * 2;
  int4* idx4 = (int4*)p; p += (size_t)E_ * 16;
  int* deg   = (int*)p; p += (size_t)N_ * 4;
  int* cnt   = (int*)p; p += (size_t)N_ * 4;

  // weight transposes: edge [R][3][64][64], node [R][2][64][64]
  k_wt<<<dim3((64 * 64 + 255) / 256, 3 * R_), 256, 0, stream>>>(edge_mlp_W, wt_edge, 64, 64);
  k_wt<<<dim3((64 * 64 + 255) / 256, 2 * R_), 256, 0, stream>>>(node_mlp_W, wt_node, 64, 64);
  k_wt<<<dim3((64 * 64 + 255) / 256, 1), 256, 0, stream>>>(dec_W, wt_dec, 64, 64);
  k_wt<<<dim3((64 * 64 + 255) / 256, 1), 256, 0, stream>>>(hm1_W, wt_hm1, 64, 64);
  k_wt<<<dim3((64 * 1024 + 255) / 256, 1), 256, 0, stream>>>(hm2_W, wt_hm2, 64, 1024);

  // dst-sorted edge order + CSR offsets
  const int e_blocks = (int)((E_ + 255) / 256);
  hipMemsetAsync(deg, 0, (size_t)N_ * 4, stream);
  k_hist<<<e_blocks, 256, 0, stream>>>(edge_index, deg, E_);
  k_scan<<<1, 1024, 0, stream>>>(deg, cnt, N_);
  k_scatter<<<e_blocks, 256, 0, stream>>>(edge_index, cnt, idx4, E_);

  const int nh_blocks = (int)(((size_t)N_ * HD + 255) / 256);
  k_node_enc<<<nh_blocks, 256, 0, stream>>>(node_features, node_enc_W, node_enc_b, h_bf, N_);

  const int netiles = (int)((E_ + 15) / 16);
  const int npairs = (netiles + 1) / 2;
  const int pe_blocks = (npairs + 3) / 4;
  const int ntiles = (N_ + 15) / 16;
  const int nblocks = (ntiles + 3) / 4;

  // H12 for round 0 (edge bias folded into H1)
  k_pre<<<nblocks, 256, 0, stream>>>(h_bf, wt_edge, edge_mlp_b, H12, ntiles);

  for (int r = 0; r < R_; ++r) {
    const unsigned short* W3t = wt_edge + (size_t)r * 3 * 4096 + 2 * 4096;
    bool fuse = (r == 0), last = (r == R_ - 1);
    if (last) hipMemsetAsync(aggr, 0, (size_t)N_ * HD * 4, stream);
    if (fuse && last)
      k_edge2<true, true><<<pe_blocks, 256, 0, stream>>>(
          e_bf, H12, idx4, W3t, edge_attr, edge_enc_W, edge_enc_b, aggr, netiles, (int)E_);
    else if (fuse)
      k_edge2<true, false><<<pe_blocks, 256, 0, stream>>>(
          e_bf, H12, idx4, W3t, edge_attr, edge_enc_W, edge_enc_b, nullptr, netiles, (int)E_);
    else if (last)
      k_edge2<false, true><<<pe_blocks, 256, 0, stream>>>(
          e_bf, H12, idx4, W3t, nullptr, nullptr, nullptr, aggr, netiles, (int)E_);
    else
      k_edge2<false, false><<<pe_blocks, 256, 0, stream>>>(
          e_bf, H12, idx4, W3t, nullptr, nullptr, nullptr, nullptr, netiles, (int)E_);

    const unsigned short* w12_next =
        (r + 1 < R_) ? (wt_edge + (size_t)(r + 1) * 3 * 4096) : nullptr;
    const float* be_next = edge_mlp_b + (size_t)(r + 1 < R_ ? r + 1 : 0) * HD;
    k_node_csr<<<nblocks, 256, 0, stream>>>(
        h_bf, e_bf, cnt, wt_node + (size_t)r * 2 * 4096,
        node_mlp_b + (size_t)r * HD, w12_next, be_next, H12,
        last ? aggr : nullptr, ntiles);
  }

  float* out_emb = (float*)d_out;
  float* out_log = out_emb + (size_t)N_ * HD;
  k_dec_hm1<<<nblocks, 256, 0, stream>>>(h_bf, wt_dec, dec_b, wt_hm1, hm1_b,
                                         out_emb, t_bf, ntiles);
  k_head_mfma<<<ntiles * 4, 256, 0, stream>>>(t_bf, wt_hm2, hm2_b, out_log);
}

// Round 12
// 771.978 us; speedup vs baseline: 1.2656x; 1.0453x over previous
//
#include <hip/hip_runtime.h>

#define HD 64

typedef __attribute__((ext_vector_type(8))) short bf16x8;
typedef __attribute__((ext_vector_type(4))) float f32x4;

#define MFMA16(a, b, c) __builtin_amdgcn_mfma_f32_16x16x32_bf16(a, b, c, 0, 0, 0)

__device__ __forceinline__ float relu(float x) { return x > 0.f ? x : 0.f; }

__device__ __forceinline__ unsigned short f2bf(float f) {
  unsigned u = __float_as_uint(f);
  u += 0x7fff + ((u >> 16) & 1);
  return (unsigned short)(u >> 16);
}
__device__ __forceinline__ float bf2f(short s) {
  return __uint_as_float(((unsigned)(unsigned short)s) << 16);
}
__device__ __forceinline__ bf16x8 ldbf8(const unsigned short* p) {
  return *reinterpret_cast<const bf16x8*>(p);
}
__device__ __forceinline__ float4 ldf4(const float* p) {
  return *reinterpret_cast<const float4*>(p);
}

// ---------- weight convert+transpose: [B][K][Nc] f32 -> [B][Nc][K] bf16 ----------
__global__ __launch_bounds__(256) void k_wt(const float* __restrict__ in,
                                            unsigned short* __restrict__ out,
                                            int K, int Nc) {
  int total = K * Nc;
  int idx = blockIdx.x * 256 + threadIdx.x;
  int b = blockIdx.y;
  if (idx >= total) return;
  int n = idx / K, k = idx - n * K;
  out[(size_t)b * total + idx] = f2bf(in[(size_t)b * total + (size_t)k * Nc + n]);
}

// ---------- CSR build ----------
__global__ __launch_bounds__(256) void k_hist(const int* __restrict__ ei,
                                              int* __restrict__ deg, long long E_) {
  long long eid = (long long)blockIdx.x * 256 + threadIdx.x;
  if (eid >= E_) return;
  atomicAdd(deg + ei[E_ + eid], 1);
}

__global__ __launch_bounds__(1024) void k_scan(const int* __restrict__ deg,
                                               int* __restrict__ cnt, int N_) {
  __shared__ int s[1024];
  int t = threadIdx.x;
  int chunk = (N_ + 1023) / 1024;
  int lo = t * chunk, hi = lo + chunk;
  if (lo > N_) lo = N_;
  if (hi > N_) hi = N_;
  int sum = 0;
  for (int i = lo; i < hi; ++i) sum += deg[i];
  s[t] = sum;
  __syncthreads();
  for (int o = 1; o < 1024; o <<= 1) {
    int v = (t >= o) ? s[t - o] : 0;
    __syncthreads();
    s[t] += v;
    __syncthreads();
  }
  int base = (t == 0) ? 0 : s[t - 1];
  for (int i = lo; i < hi; ++i) {
    cnt[i] = base;
    base += deg[i];
  }
}

// packs (perm, src, dst) into one int4 -> 1 write-allocate line per edge, 1 load per consumer
__global__ __launch_bounds__(256) void k_scatter(const int* __restrict__ ei,
                                                 int* __restrict__ cnt,
                                                 int4* __restrict__ idx4, long long E_) {
  long long eid = (long long)blockIdx.x * 256 + threadIdx.x;
  if (eid >= E_) return;
  int s = ei[eid], d = ei[E_ + eid];
  int pos = atomicAdd(cnt + d, 1);
  idx4[pos] = make_int4((int)eid, s, d, 0);
}
// after k_scatter: cnt[n] == end offset of node n's edge range; start = cnt[n-1]

// ---------- node encoder ----------
__global__ __launch_bounds__(256) void k_node_enc(
    const float* __restrict__ nf, const float* __restrict__ W,
    const float* __restrict__ b, unsigned short* __restrict__ h, int N_) {
  int t = blockIdx.x * 256 + threadIdx.x;
  int n = t >> 6, j = t & 63;
  if (n >= N_) return;
  float x0 = nf[(size_t)n * 2 + 0], x1 = nf[(size_t)n * 2 + 1];
  h[t] = f2bf(relu(fmaf(x0, W[j], fmaf(x1, W[HD + j], b[j]))));
}

// ---------- round-0 precompute: H12 = [h@W1 + b_edge | h@W2] bf16 [N][128] ----------
__global__ __launch_bounds__(256) void k_pre(
    const unsigned short* __restrict__ h, const unsigned short* __restrict__ W12t,
    const float* __restrict__ be0, unsigned short* __restrict__ H12, int ntiles) {
  __shared__ __align__(16) float s[4][16][68];
  int wid = threadIdx.x >> 6, l = threadIdx.x & 63;
  int tile = blockIdx.x * 4 + wid;
  int lr = l & 15, lk = l >> 4;
  if (tile >= ntiles) return;
  int r0 = tile * 16;
  const unsigned short* hp = h + (size_t)(r0 + lr) * HD;
  f32x4 a1[4] = {}, a2[4] = {};
#pragma unroll
  for (int kk = 0; kk < 2; ++kk) {
    bf16x8 a = ldbf8(hp + kk * 32 + lk * 8);
#pragma unroll
    for (int nt = 0; nt < 4; ++nt) {
      bf16x8 b1 = ldbf8(W12t + (size_t)(nt * 16 + lr) * 64 + kk * 32 + lk * 8);
      bf16x8 b2 = ldbf8(W12t + 4096 + (size_t)(nt * 16 + lr) * 64 + kk * 32 + lk * 8);
      a1[nt] = MFMA16(a, b1, a1[nt]);
      a2[nt] = MFMA16(a, b2, a2[nt]);
    }
  }
  int erow = l >> 2, c0 = (l & 3) * 16;
#pragma unroll
  for (int nt = 0; nt < 4; ++nt) {
    float bias = be0[nt * 16 + lr];
#pragma unroll
    for (int i = 0; i < 4; ++i) s[wid][lk * 4 + i][nt * 16 + lr] = a1[nt][i] + bias;
  }
  {
    bf16x8 o0, o1;
#pragma unroll
    for (int j = 0; j < 8; ++j) {
      o0[j] = f2bf(s[wid][erow][c0 + j]);
      o1[j] = f2bf(s[wid][erow][c0 + 8 + j]);
    }
    unsigned short* op = H12 + (size_t)(r0 + erow) * 128 + c0;
    *reinterpret_cast<bf16x8*>(op) = o0;
    *reinterpret_cast<bf16x8*>(op + 8) = o1;
  }
#pragma unroll
  for (int nt = 0; nt < 4; ++nt)
#pragma unroll
    for (int i = 0; i < 4; ++i) s[wid][lk * 4 + i][nt * 16 + lr] = a2[nt][i];
  {
    bf16x8 o0, o1;
#pragma unroll
    for (int j = 0; j < 8; ++j) {
      o0[j] = f2bf(s[wid][erow][c0 + j]);
      o1[j] = f2bf(s[wid][erow][c0 + 8 + j]);
    }
    unsigned short* op = H12 + (size_t)(r0 + erow) * 128 + 64 + c0;
    *reinterpret_cast<bf16x8*>(op) = o0;
    *reinterpret_cast<bf16x8*>(op + 8) = o1;
  }
}

// ---------- edge kernel: m = relu(H1[src] + H2[dst] + e@W3); 2 tiles/wave ILP ----------
// Single shared [16][68] transpose buffer (combine phases sequential) -> 17.4 KB LDS.
// Gathers for both tiles issued up-front (the latency-critical part).
template <bool FUSE_ENC>
__global__ __launch_bounds__(256) void k_edge2(
    unsigned short* __restrict__ e, const unsigned short* __restrict__ H12,
    const int4* __restrict__ idx4, const unsigned short* __restrict__ W3t,
    const float* __restrict__ ea, const float* __restrict__ We,
    const float* __restrict__ be, int netiles, int E_) {
  __shared__ __align__(16) float smf[4][16][68];
  int wid = threadIdx.x >> 6, l = threadIdx.x & 63;
  int tp = blockIdx.x * 4 + wid;  // tile pair
  int lr = l & 15, lk = l >> 4;
  int erow = l >> 2, c0 = (l & 3) * 16;
  int t0 = tp * 2;
  if (t0 >= netiles) return;

  int r0[2] = {t0 * 16, (t0 + 1) * 16};
  bool tv[2] = {true, (t0 + 1) < netiles};

  // ---- early gathers for both tiles (independent chains) ----
  bf16x8 g1a[2], g1b[2], g2a[2], g2b[2];
#pragma unroll
  for (int u = 0; u < 2; ++u) {
    int4 q = idx4[min(r0[u] + erow, E_ - 1)];
    const unsigned short* h1p = H12 + (size_t)q.y * 128 + c0;
    const unsigned short* h2p = H12 + (size_t)q.z * 128 + 64 + c0;
    g1a[u] = ldbf8(h1p);
    g1b[u] = ldbf8(h1p + 8);
    g2a[u] = ldbf8(h2p);
    g2b[u] = ldbf8(h2p + 8);
  }

  // ---- A fragments for both tiles ----
  bf16x8 afrag[2][2];
#pragma unroll
  for (int u = 0; u < 2; ++u) {
    int ia = min(r0[u] + lr, E_ - 1);
    if (FUSE_ENC) {
      int eid = idx4[ia].x;
      float4 row = ldf4(ea + (size_t)eid * 4);
#pragma unroll
      for (int kk = 0; kk < 2; ++kk) {
        int j0 = kk * 32 + lk * 8;
        float4 b0 = ldf4(be + j0), b1 = ldf4(be + j0 + 4);
        float v[8] = {b0.x, b0.y, b0.z, b0.w, b1.x, b1.y, b1.z, b1.w};
#pragma unroll
        for (int c = 0; c < 4; ++c) {
          float x = (c == 0) ? row.x : (c == 1) ? row.y : (c == 2) ? row.z : row.w;
          float4 w0 = ldf4(We + c * 64 + j0), w1 = ldf4(We + c * 64 + j0 + 4);
          v[0] = fmaf(x, w0.x, v[0]); v[1] = fmaf(x, w0.y, v[1]);
          v[2] = fmaf(x, w0.z, v[2]); v[3] = fmaf(x, w0.w, v[3]);
          v[4] = fmaf(x, w1.x, v[4]); v[5] = fmaf(x, w1.y, v[5]);
          v[6] = fmaf(x, w1.z, v[6]); v[7] = fmaf(x, w1.w, v[7]);
        }
#pragma unroll
        for (int q = 0; q < 8; ++q) afrag[u][kk][q] = (short)f2bf(relu(v[q]));
      }
    } else {
      const unsigned short* ep = e + (size_t)ia * HD;
      afrag[u][0] = ldbf8(ep + lk * 8);
      afrag[u][1] = ldbf8(ep + 32 + lk * 8);
    }
  }

  // ---- e @ W3 for both tiles (W3 fragments shared) ----
  f32x4 acc0[4] = {}, acc1[4] = {};
#pragma unroll
  for (int kk = 0; kk < 2; ++kk) {
#pragma unroll
    for (int nt = 0; nt < 4; ++nt) {
      bf16x8 bb = ldbf8(W3t + (size_t)(nt * 16 + lr) * 64 + kk * 32 + lk * 8);
      acc0[nt] = MFMA16(afrag[0][kk], bb, acc0[nt]);
      acc1[nt] = MFMA16(afrag[1][kk], bb, acc1[nt]);
    }
  }

  // ---- sequential combine per tile through ONE shared buffer (wave-private) ----
#pragma unroll
  for (int u = 0; u < 2; ++u) {
    if (!tv[u]) continue;
#pragma unroll
    for (int nt = 0; nt < 4; ++nt)
#pragma unroll
      for (int i = 0; i < 4; ++i)
        smf[wid][lk * 4 + i][nt * 16 + lr] = (u == 0) ? acc0[nt][i] : acc1[nt][i];
    float g1f[16], g2f[16];
#pragma unroll
    for (int j = 0; j < 8; ++j) {
      g1f[j] = bf2f(g1a[u][j]); g1f[8 + j] = bf2f(g1b[u][j]);
      g2f[j] = bf2f(g2a[u][j]); g2f[8 + j] = bf2f(g2b[u][j]);
    }
    bf16x8 o0, o1;
#pragma unroll
    for (int q = 0; q < 4; ++q) {
      float4 s4 = ldf4(&smf[wid][erow][c0 + q * 4]);
      float v0 = relu(s4.x + g1f[q * 4 + 0] + g2f[q * 4 + 0]);
      float v1 = relu(s4.y + g1f[q * 4 + 1] + g2f[q * 4 + 1]);
      float v2 = relu(s4.z + g1f[q * 4 + 2] + g2f[q * 4 + 2]);
      float v3 = relu(s4.w + g1f[q * 4 + 3] + g2f[q * 4 + 3]);
      if (q < 2) {
        o0[q * 4 + 0] = f2bf(v0); o0[q * 4 + 1] = f2bf(v1);
        o0[q * 4 + 2] = f2bf(v2); o0[q * 4 + 3] = f2bf(v3);
      } else {
        o1[(q - 2) * 4 + 0] = f2bf(v0); o1[(q - 2) * 4 + 1] = f2bf(v1);
        o1[(q - 2) * 4 + 2] = f2bf(v2); o1[(q - 2) * 4 + 3] = f2bf(v3);
      }
    }
    size_t eb = ((size_t)r0[u] + erow) * HD + c0;
    *reinterpret_cast<bf16x8*>(&e[eb]) = o0;
    *reinterpret_cast<bf16x8*>(&e[eb + 8]) = o1;
  }
}

// ---------- node kernel: CSR aggregation + node MLP + fused next-round H12 ----------
__global__ __launch_bounds__(256) void k_node_csr(
    unsigned short* __restrict__ h, const unsigned short* __restrict__ m,
    const int* __restrict__ cnt,  // end offsets
    const unsigned short* __restrict__ Wt, const float* __restrict__ b,
    const unsigned short* __restrict__ W12t,  // next round [W1|W2], or null
    const float* __restrict__ be_next,        // next round edge bias
    unsigned short* __restrict__ H12, int ntiles) {
  __shared__ __align__(16) float smf[4][16][68];
  int wid = threadIdx.x >> 6, l = threadIdx.x & 63;
  int tile = blockIdx.x * 4 + wid;
  if (tile >= ntiles) return;
  int r0 = tile * 16;
  int lr = l & 15, lk = l >> 4;

  // ---- CSR aggregation: 4 lanes per node, 16 cols per lane ----
  int node = r0 + lr;
  int q16 = lk * 16;
  int beg = (node == 0) ? 0 : cnt[node - 1];
  int end = cnt[node];
  float s0[16];
#pragma unroll
  for (int j = 0; j < 16; ++j) s0[j] = 0.f;
  for (int i = beg; i < end; ++i) {
    const unsigned short* mp = m + (size_t)i * HD + q16;
    bf16x8 v0 = ldbf8(mp);
    bf16x8 v1 = ldbf8(mp + 8);
#pragma unroll
    for (int j = 0; j < 8; ++j) {
      s0[j] += bf2f(v0[j]);
      s0[8 + j] += bf2f(v1[j]);
    }
  }
#pragma unroll
  for (int j = 0; j < 16; ++j) smf[wid][lr][q16 + j] = s0[j];

  // ---- A-fragments: aggr from LDS, h from global ----
  bf16x8 aagg[2];
#pragma unroll
  for (int kk = 0; kk < 2; ++kk) {
    const float* sp = &smf[wid][lr][kk * 32 + lk * 8];
    float4 f0 = ldf4(sp), f1 = ldf4(sp + 4);
    aagg[kk][0] = f2bf(f0.x); aagg[kk][1] = f2bf(f0.y);
    aagg[kk][2] = f2bf(f0.z); aagg[kk][3] = f2bf(f0.w);
    aagg[kk][4] = f2bf(f1.x); aagg[kk][5] = f2bf(f1.y);
    aagg[kk][6] = f2bf(f1.z); aagg[kk][7] = f2bf(f1.w);
  }

  f32x4 acc[4] = {};
#pragma unroll
  for (int kk = 0; kk < 4; ++kk) {
    bf16x8 a = (kk < 2) ? ldbf8(h + (size_t)(r0 + lr) * HD + kk * 32 + lk * 8)
                        : aagg[kk - 2];
#pragma unroll
    for (int nt = 0; nt < 4; ++nt) {
      bf16x8 bb = ldbf8(Wt + (size_t)(kk >> 1) * 4096 +
                        (size_t)(nt * 16 + lr) * 64 + (kk & 1) * 32 + lk * 8);
      acc[nt] = MFMA16(a, bb, acc[nt]);
    }
  }

  // ---- relu + transpose -> new h ----
#pragma unroll
  for (int nt = 0; nt < 4; ++nt) {
    float bias = b[nt * 16 + lr];
#pragma unroll
    for (int i = 0; i < 4; ++i)
      smf[wid][lk * 4 + i][nt * 16 + lr] = relu(acc[nt][i] + bias);
  }
  int erow = l >> 2, c0 = (l & 3) * 16;
  {
    bf16x8 o0, o1;
#pragma unroll
    for (int j = 0; j < 8; ++j) {
      o0[j] = f2bf(smf[wid][erow][c0 + j]);
      o1[j] = f2bf(smf[wid][erow][c0 + 8 + j]);
    }
    size_t hb = (size_t)(r0 + erow) * HD + c0;
    *reinterpret_cast<bf16x8*>(&h[hb]) = o0;
    *reinterpret_cast<bf16x8*>(&h[hb + 8]) = o1;
  }

  if (!W12t) return;

  // ---- fused next-round H12 = [h@W1 + be_next | h@W2] bf16 ----
  bf16x8 ah[2];
#pragma unroll
  for (int kk = 0; kk < 2; ++kk) {
    const float* sp = &smf[wid][lr][kk * 32 + lk * 8];
    float4 f0 = ldf4(sp), f1 = ldf4(sp + 4);
    ah[kk][0] = f2bf(f0.x); ah[kk][1] = f2bf(f0.y);
    ah[kk][2] = f2bf(f0.z); ah[kk][3] = f2bf(f0.w);
    ah[kk][4] = f2bf(f1.x); ah[kk][5] = f2bf(f1.y);
    ah[kk][6] = f2bf(f1.z); ah[kk][7] = f2bf(f1.w);
  }
  f32x4 a1[4] = {}, a2[4] = {};
#pragma unroll
  for (int kk = 0; kk < 2; ++kk) {
#pragma unroll
    for (int nt = 0; nt < 4; ++nt) {
      bf16x8 b1 = ldbf8(W12t + (size_t)(nt * 16 + lr) * 64 + kk * 32 + lk * 8);
      bf16x8 b2 = ldbf8(W12t + 4096 + (size_t)(nt * 16 + lr) * 64 + kk * 32 + lk * 8);
      a1[nt] = MFMA16(ah[kk], b1, a1[nt]);
      a2[nt] = MFMA16(ah[kk], b2, a2[nt]);
    }
  }
#pragma unroll
  for (int nt = 0; nt < 4; ++nt) {
    float bias = be_next[nt * 16 + lr];
#pragma unroll
    for (int i = 0; i < 4; ++i)
      smf[wid][lk * 4 + i][nt * 16 + lr] = a1[nt][i] + bias;
  }
  {
    bf16x8 o0, o1;
#pragma unroll
    for (int j = 0; j < 8; ++j) {
      o0[j] = f2bf(smf[wid][erow][c0 + j]);
      o1[j] = f2bf(smf[wid][erow][c0 + 8 + j]);
    }
    unsigned short* op = H12 + (size_t)(r0 + erow) * 128 + c0;
    *reinterpret_cast<bf16x8*>(op) = o0;
    *reinterpret_cast<bf16x8*>(op + 8) = o1;
  }
#pragma unroll
  for (int nt = 0; nt < 4; ++nt)
#pragma unroll
    for (int i = 0; i < 4; ++i)
      smf[wid][lk * 4 + i][nt * 16 + lr] = a2[nt][i];
  {
    bf16x8 o0, o1;
#pragma unroll
    for (int j = 0; j < 8; ++j) {
      o0[j] = f2bf(smf[wid][erow][c0 + j]);
      o1[j] = f2bf(smf[wid][erow][c0 + 8 + j]);
    }
    unsigned short* op = H12 + (size_t)(r0 + erow) * 128 + 64 + c0;
    *reinterpret_cast<bf16x8*>(op) = o0;
    *reinterpret_cast<bf16x8*>(op + 8) = o1;
  }
}

// ---------- fused decoder + hm1: emb = h@Wdec + b (fp32 out), t = relu(emb@Whm1 + b) ----------
__global__ __launch_bounds__(256) void k_dec_hm1(
    const unsigned short* __restrict__ h,
    const unsigned short* __restrict__ Wdec, const float* __restrict__ bdec,
    const unsigned short* __restrict__ Whm1, const float* __restrict__ bhm1,
    float* __restrict__ emb, unsigned short* __restrict__ t_bf, int ntiles) {
  __shared__ __align__(16) float smf[4][16][68];
  int wid = threadIdx.x >> 6, l = threadIdx.x & 63;
  int tile = blockIdx.x * 4 + wid;
  if (tile >= ntiles) return;
  int r0 = tile * 16;
  int lr = l & 15, lk = l >> 4;
  int erow = l >> 2, c0 = (l & 3) * 16;

  f32x4 acc[4] = {};
#pragma unroll
  for (int kk = 0; kk < 2; ++kk) {
    bf16x8 a = ldbf8(h + (size_t)(r0 + lr) * HD + kk * 32 + lk * 8);
#pragma unroll
    for (int nt = 0; nt < 4; ++nt) {
      bf16x8 bb = ldbf8(Wdec + (size_t)(nt * 16 + lr) * HD + kk * 32 + lk * 8);
      acc[nt] = MFMA16(a, bb, acc[nt]);
    }
  }
#pragma unroll
  for (int nt = 0; nt < 4; ++nt) {
    float bias = bdec[nt * 16 + lr];
#pragma unroll
    for (int i = 0; i < 4; ++i)
      smf[wid][lk * 4 + i][nt * 16 + lr] = acc[nt][i] + bias;
  }
  // emb fp32 out (coalesced)
#pragma unroll
  for (int q = 0; q < 4; ++q)
    *reinterpret_cast<float4*>(emb + (size_t)(r0 + erow) * HD + c0 + q * 4) =
        ldf4(&smf[wid][erow][c0 + q * 4]);
  // hm1 A-fragments from LDS
  bf16x8 ah[2];
#pragma unroll
  for (int kk = 0; kk < 2; ++kk) {
    const float* sp = &smf[wid][lr][kk * 32 + lk * 8];
    float4 f0 = ldf4(sp), f1 = ldf4(sp + 4);
    ah[kk][0] = f2bf(f0.x); ah[kk][1] = f2bf(f0.y);
    ah[kk][2] = f2bf(f0.z); ah[kk][3] = f2bf(f0.w);
    ah[kk][4] = f2bf(f1.x); ah[kk][5] = f2bf(f1.y);
    ah[kk][6] = f2bf(f1.z); ah[kk][7] = f2bf(f1.w);
  }
  f32x4 acc2[4] = {};
#pragma unroll
  for (int kk = 0; kk < 2; ++kk) {
#pragma unroll
    for (int nt = 0; nt < 4; ++nt) {
      bf16x8 bb = ldbf8(Whm1 + (size_t)(nt * 16 + lr) * HD + kk * 32 + lk * 8);
      acc2[nt] = MFMA16(ah[kk], bb, acc2[nt]);
    }
  }
#pragma unroll
  for (int nt = 0; nt < 4; ++nt) {
    float bias = bhm1[nt * 16 + lr];
#pragma unroll
    for (int i = 0; i < 4; ++i)
      smf[wid][lk * 4 + i][nt * 16 + lr] = relu(acc2[nt][i] + bias);
  }
  {
    bf16x8 o0, o1;
#pragma unroll
    for (int j = 0; j < 8; ++j) {
      o0[j] = f2bf(smf[wid][erow][c0 + j]);
      o1[j] = f2bf(smf[wid][erow][c0 + 8 + j]);
    }
    size_t tb = (size_t)(r0 + erow) * HD + c0;
    *reinterpret_cast<bf16x8*>(&t_bf[tb]) = o0;
    *reinterpret_cast<bf16x8*>(&t_bf[tb + 8]) = o1;
  }
}

// ---------- heatmap head: [N,64] @ [64,1024] + b (plain coalesced stores) ----------
__global__ __launch_bounds__(256) void k_head_mfma(
    const unsigned short* __restrict__ A, const unsigned short* __restrict__ Wt,
    const float* __restrict__ b2, float* __restrict__ out) {
  __shared__ __align__(16) float sf[4][16][68];
  int wid = threadIdx.x >> 6, l = threadIdx.x & 63;
  int task = blockIdx.x * 4 + wid;
  int mt = task >> 4, ng = task & 15;
  int r0 = mt * 16, n0 = ng * 64;
  int lr = l & 15, lk = l >> 4;

  f32x4 acc[4] = {};
#pragma unroll
  for (int kk = 0; kk < 2; ++kk) {
    bf16x8 a = ldbf8(A + (size_t)(r0 + lr) * HD + kk * 32 + lk * 8);
#pragma unroll
    for (int nt = 0; nt < 4; ++nt) {
      bf16x8 bb = ldbf8(Wt + (size_t)(n0 + nt * 16 + lr) * HD + kk * 32 + lk * 8);
      acc[nt] = MFMA16(a, bb, acc[nt]);
    }
  }
#pragma unroll
  for (int nt = 0; nt < 4; ++nt) {
    int col = nt * 16 + lr;
    float bias = b2[n0 + col];
#pragma unroll
    for (int i = 0; i < 4; ++i) sf[wid][lk * 4 + i][col] = acc[nt][i] + bias;
  }
  int row = l >> 2, cb = (l & 3) * 16;
  float* op = out + (size_t)(r0 + row) * 1024 + n0 + cb;
#pragma unroll
  for (int q = 0; q < 4; ++q)
    *reinterpret_cast<float4*>(op + q * 4) = ldf4(&sf[wid][row][cb + q * 4]);
}

extern "C" void kernel_launch(void* const* d_in, const int* in_sizes, int n_in,
                              void* d_out, int out_size, void* d_ws, size_t ws_size,
                              hipStream_t stream) {
  const float* node_features = (const float*)d_in[0];
  const float* edge_attr     = (const float*)d_in[1];
  const float* node_enc_W    = (const float*)d_in[2];
  const float* node_enc_b    = (const float*)d_in[3];
  const float* edge_enc_W    = (const float*)d_in[4];
  const float* edge_enc_b    = (const float*)d_in[5];
  const float* edge_mlp_W    = (const float*)d_in[6];
  const float* edge_mlp_b    = (const float*)d_in[7];
  const float* node_mlp_W    = (const float*)d_in[8];
  const float* node_mlp_b    = (const float*)d_in[9];
  const float* dec_W         = (const float*)d_in[10];
  const float* dec_b         = (const float*)d_in[11];
  const float* hm1_W         = (const float*)d_in[12];
  const float* hm1_b         = (const float*)d_in[13];
  const float* hm2_W         = (const float*)d_in[14];
  const float* hm2_b         = (const float*)d_in[15];
  const int*   edge_index    = (const int*)d_in[16];

  const int N_ = in_sizes[0] / 2;
  const long long E_ = in_sizes[1] / 4;
  const int R_ = in_sizes[7] / HD;

  // workspace carve-up (16B aligned chunks)
  char* p = (char*)d_ws;
  unsigned short* e_bf = (unsigned short*)p; p += (size_t)E_ * HD * 2;
  unsigned short* h_bf = (unsigned short*)p; p += (size_t)N_ * HD * 2;
  unsigned short* H12  = (unsigned short*)p; p += (size_t)N_ * 128 * 2;
  unsigned short* t_bf = (unsigned short*)p; p += (size_t)N_ * HD * 2;
  unsigned short* wt_edge = (unsigned short*)p; p += (size_t)R_ * 3 * 64 * 64 * 2;
  unsigned short* wt_node = (unsigned short*)p; p += (size_t)R_ * 2 * 64 * 64 * 2;
  unsigned short* wt_dec = (unsigned short*)p;  p += 64 * 64 * 2;
  unsigned short* wt_hm1 = (unsigned short*)p;  p += 64 * 64 * 2;
  unsigned short* wt_hm2 = (unsigned short*)p;  p += 1024 * 64 * 2;
  int4* idx4 = (int4*)p; p += (size_t)E_ * 16;
  int* deg   = (int*)p; p += (size_t)N_ * 4;
  int* cnt   = (int*)p; p += (size_t)N_ * 4;

  // weight transposes: edge [R][3][64][64], node [R][2][64][64]
  k_wt<<<dim3((64 * 64 + 255) / 256, 3 * R_), 256, 0, stream>>>(edge_mlp_W, wt_edge, 64, 64);
  k_wt<<<dim3((64 * 64 + 255) / 256, 2 * R_), 256, 0, stream>>>(node_mlp_W, wt_node, 64, 64);
  k_wt<<<dim3((64 * 64 + 255) / 256, 1), 256, 0, stream>>>(dec_W, wt_dec, 64, 64);
  k_wt<<<dim3((64 * 64 + 255) / 256, 1), 256, 0, stream>>>(hm1_W, wt_hm1, 64, 64);
  k_wt<<<dim3((64 * 1024 + 255) / 256, 1), 256, 0, stream>>>(hm2_W, wt_hm2, 64, 1024);

  // dst-sorted edge order + CSR offsets
  const int e_blocks = (int)((E_ + 255) / 256);
  hipMemsetAsync(deg, 0, (size_t)N_ * 4, stream);
  k_hist<<<e_blocks, 256, 0, stream>>>(edge_index, deg, E_);
  k_scan<<<1, 1024, 0, stream>>>(deg, cnt, N_);
  k_scatter<<<e_blocks, 256, 0, stream>>>(edge_index, cnt, idx4, E_);

  const int nh_blocks = (int)(((size_t)N_ * HD + 255) / 256);
  k_node_enc<<<nh_blocks, 256, 0, stream>>>(node_features, node_enc_W, node_enc_b, h_bf, N_);

  const int netiles = (int)((E_ + 15) / 16);
  const int npairs = (netiles + 1) / 2;
  const int pe_blocks = (npairs + 3) / 4;
  const int ntiles = (N_ + 15) / 16;
  const int nblocks = (ntiles + 3) / 4;

  // H12 for round 0 (edge bias folded into H1)
  k_pre<<<nblocks, 256, 0, stream>>>(h_bf, wt_edge, edge_mlp_b, H12, ntiles);

  for (int r = 0; r < R_; ++r) {
    const unsigned short* W3t = wt_edge + (size_t)r * 3 * 4096 + 2 * 4096;
    if (r == 0) {
      k_edge2<true><<<pe_blocks, 256, 0, stream>>>(
          e_bf, H12, idx4, W3t, edge_attr, edge_enc_W, edge_enc_b, netiles, (int)E_);
    } else {
      k_edge2<false><<<pe_blocks, 256, 0, stream>>>(
          e_bf, H12, idx4, W3t, nullptr, nullptr, nullptr, netiles, (int)E_);
    }
    const unsigned short* w12_next =
        (r + 1 < R_) ? (wt_edge + (size_t)(r + 1) * 3 * 4096) : nullptr;
    const float* be_next = edge_mlp_b + (size_t)(r + 1 < R_ ? r + 1 : 0) * HD;
    k_node_csr<<<nblocks, 256, 0, stream>>>(
        h_bf, e_bf, cnt, wt_node + (size_t)r * 2 * 4096,
        node_mlp_b + (size_t)r * HD, w12_next, be_next, H12, ntiles);
  }

  float* out_emb = (float*)d_out;
  float* out_log = out_emb + (size_t)N_ * HD;
  k_dec_hm1<<<nblocks, 256, 0, stream>>>(h_bf, wt_dec, dec_b, wt_hm1, hm1_b,
                                         out_emb, t_bf, ntiles);
  k_head_mfma<<<ntiles * 4, 256, 0, stream>>>(t_bf, wt_hm2, hm2_b, out_log);
}